// Round 1
// baseline (26.064 us; speedup 1.0000x reference)
//
#include <hip/hip_runtime.h>
#include <math.h>

// Problem constants (from reference setup_inputs: B=8, H=W=512, N=50).
constexpr int B = 8, H = 512, W = 512, N = 50;
constexpr int ROWS_PER_BLOCK = 4;   // 4 rows of 512 px per 256-thread block
constexpr int PX = 8;               // pixels per thread (64 threads cover a row)
constexpr int NBLOCKS = (B * H) / ROWS_PER_BLOCK;  // 1024

// Kernel 1: per-pixel nearest-point mask + per-block partial loss sum.
// Points staged in LDS as float2 (already converted); all distance math in
// fp32 on exact small integers -> bit-exact vs integer arithmetic.
__global__ __launch_bounds__(256) void psl_main(
    const float* __restrict__ out,
    const int*   __restrict__ pos,
    const int*   __restrict__ neg,
    float*       __restrict__ dout,
    float*       __restrict__ partials)
{
    __shared__ float2 s_pos[N];
    __shared__ float2 s_neg[N];
    __shared__ float  s_red[4];

    const int bid = blockIdx.x;      // 0..1023
    const int t   = threadIdx.x;
    const int b      = bid >> 7;     // 128 blocks per batch (512/4 rows)
    const int rowblk = bid & 127;

    if (t < N) {
        int2 p = ((const int2*)pos)[b * N + t];
        s_pos[t] = make_float2((float)p.x, (float)p.y);   // (py, px)
    } else if (t < 2 * N) {
        int2 p = ((const int2*)neg)[b * N + (t - N)];
        s_neg[t - N] = make_float2((float)p.x, (float)p.y);
    }
    __syncthreads();

    const int wave = t >> 6;         // 0..3  (wave id == row within block)
    const int lane = t & 63;         // 0..63
    const int y  = rowblk * ROWS_PER_BLOCK + wave;
    const int x0 = lane * PX;
    const float yf  = (float)y;
    const float x0f = (float)x0;

    float minp[PX], minn[PX];
    #pragma unroll
    for (int j = 0; j < PX; ++j) { minp[j] = 3.0e38f; minn[j] = 3.0e38f; }

    #pragma unroll 5
    for (int n = 0; n < N; ++n) {
        float2 p = s_pos[n];
        float dy = yf - p.x;
        float a  = dy * dy;
        float dx = x0f - p.y;
        #pragma unroll
        for (int j = 0; j < PX; ++j) {
            float d2 = fmaf(dx, dx, a);
            minp[j] = fminf(minp[j], d2);
            dx += 1.0f;
        }
    }
    #pragma unroll 5
    for (int n = 0; n < N; ++n) {
        float2 p = s_neg[n];
        float dy = yf - p.x;
        float a  = dy * dy;
        float dx = x0f - p.y;
        #pragma unroll
        for (int j = 0; j < PX; ++j) {
            float d2 = fmaf(dx, dx, a);
            minn[j] = fminf(minn[j], d2);
            dx += 1.0f;
        }
    }

    const size_t pix_base = ((size_t)b * H + y) * W + x0;

    // out is 16B-aligned at pix_base (x0 % 8 == 0) -> two float4 loads.
    float4 xv0 = ((const float4*)(out + pix_base))[0];
    float4 xv1 = ((const float4*)(out + pix_base))[1];
    float xs[PX] = {xv0.x, xv0.y, xv0.z, xv0.w, xv1.x, xv1.y, xv1.z, xv1.w};

    float lsum = 0.0f;
    #pragma unroll
    for (int j = 0; j < PX; ++j) {
        float z = (minp[j] < minn[j]) ? 1.0f : 0.0f;
        // d_out layout: [loss][mask...] -> mask starts at +1 (scalar stores;
        // +1 breaks 16B alignment so no float4 here).
        dout[1 + pix_base + j] = z;
        float x = xs[j];
        float term = fmaxf(x, 0.0f) - x * z + log1pf(__expf(-fabsf(x)));
        lsum += term;
    }

    // Deterministic block reduction: shfl tree within wave, LDS across waves.
    #pragma unroll
    for (int off = 32; off > 0; off >>= 1)
        lsum += __shfl_down(lsum, off, 64);
    if (lane == 0) s_red[wave] = lsum;
    __syncthreads();
    if (t == 0)
        partials[bid] = (s_red[0] + s_red[1]) + (s_red[2] + s_red[3]);
}

// Kernel 2: deterministic final reduction of 1024 block partials -> mean.
__global__ __launch_bounds__(256) void psl_finish(
    const float* __restrict__ partials,
    float*       __restrict__ dout)
{
    __shared__ float s_red[4];
    const int t = threadIdx.x;
    float s = (partials[t] + partials[t + 256]) +
              (partials[t + 512] + partials[t + 768]);
    #pragma unroll
    for (int off = 32; off > 0; off >>= 1)
        s += __shfl_down(s, off, 64);
    if ((t & 63) == 0) s_red[t >> 6] = s;
    __syncthreads();
    if (t == 0)
        dout[0] = ((s_red[0] + s_red[1]) + (s_red[2] + s_red[3])) *
                  (1.0f / (float)(B * H * W));
}

extern "C" void kernel_launch(void* const* d_in, const int* in_sizes, int n_in,
                              void* d_out, int out_size, void* d_ws, size_t ws_size,
                              hipStream_t stream) {
    const float* out_logits = (const float*)d_in[0];
    const int*   pos        = (const int*)d_in[1];
    const int*   neg        = (const int*)d_in[2];
    float* dout     = (float*)d_out;
    float* partials = (float*)d_ws;   // 1024 floats

    psl_main<<<NBLOCKS, 256, 0, stream>>>(out_logits, pos, neg, dout, partials);
    psl_finish<<<1, 256, 0, stream>>>(partials, dout);
}

// Round 2
// 21.963 us; speedup vs baseline: 1.1867x; 1.1867x over previous
//
#include <hip/hip_runtime.h>
#include <math.h>

// Problem constants (from reference setup_inputs: B=8, H=W=512, N=50).
constexpr int B = 8, H = 512, W = 512, N = 50;
constexpr int PX = 4;                       // pixels per thread
constexpr int NBLOCKS = (B * H) / 2;        // 4 waves/block, each wave = half row -> 2 rows/block

// Nearest-point mask via the reference's own decomposition:
//   d2 = p2 + (q2 - 2 px*x - 2 py*y);  p2 common across points -> compare
//   score = q2 - 2px*x - 2py*y only. All terms exact integers in fp32
//   (< 2^22), so the mask is bit-exact vs the reference.
__global__ __launch_bounds__(256) void psl_main(
    const float* __restrict__ out,
    const int*   __restrict__ pos,
    const int*   __restrict__ neg,
    float*       __restrict__ dout,
    float*       __restrict__ partials)
{
    __shared__ float4 s_pos[N];   // {-2*xc, -2*yc, xc^2+yc^2, 0}
    __shared__ float4 s_neg[N];
    __shared__ float  s_red[4];

    const int bid = blockIdx.x;          // 0..2047
    const int t   = threadIdx.x;
    const int b       = bid >> 8;        // 256 blocks per batch (512 rows / 2)
    const int rowpair = bid & 255;

    if (t < N) {
        int2 p = ((const int2*)pos)[b * N + t];        // (ycoord, xcoord)
        float fy = (float)p.x, fx = (float)p.y;
        s_pos[t] = make_float4(-2.0f * fx, -2.0f * fy, fx * fx + fy * fy, 0.0f);
    } else if (t < 2 * N) {
        int2 p = ((const int2*)neg)[b * N + (t - N)];
        float fy = (float)p.x, fx = (float)p.y;
        s_neg[t - N] = make_float4(-2.0f * fx, -2.0f * fy, fx * fx + fy * fy, 0.0f);
    }
    __syncthreads();

    const int wave = t >> 6;             // 0..3
    const int lane = t & 63;
    const int y  = rowpair * 2 + (wave >> 1);
    const int x0 = (wave & 1) * 256 + lane * PX;
    const float yf = (float)y;

    float xj[PX];
    #pragma unroll
    for (int j = 0; j < PX; ++j) xj[j] = (float)(x0 + j);

    float minp[PX], minn[PX];
    #pragma unroll
    for (int j = 0; j < PX; ++j) { minp[j] = 3.0e38f; minn[j] = 3.0e38f; }

    #pragma unroll 5
    for (int n = 0; n < N; ++n) {
        float4 P = s_pos[n];
        float cp = fmaf(P.y, yf, P.z);   // q2 - 2py*y   (exact integer)
        #pragma unroll
        for (int j = 0; j < PX; ++j)
            minp[j] = fminf(minp[j], fmaf(P.x, xj[j], cp));
        float4 Q = s_neg[n];
        float cn = fmaf(Q.y, yf, Q.z);
        #pragma unroll
        for (int j = 0; j < PX; ++j)
            minn[j] = fminf(minn[j], fmaf(Q.x, xj[j], cn));
    }

    const size_t pix_base = ((size_t)b * H + y) * W + x0;

    float4 xv = *(const float4*)(out + pix_base);   // 16B-aligned (x0 % 4 == 0, base % 4 == 0 -> x0*4 % 16 == 0)
    float xs[PX] = {xv.x, xv.y, xv.z, xv.w};

    float lsum = 0.0f;
    #pragma unroll
    for (int j = 0; j < PX; ++j) {
        float z = (minp[j] < minn[j]) ? 1.0f : 0.0f;
        dout[1 + pix_base + j] = z;      // mask starts at d_out+1 (after loss scalar)
        float x = xs[j];
        float term = fmaxf(x, 0.0f) - x * z + __logf(1.0f + __expf(-fabsf(x)));
        lsum += term;
    }

    // Deterministic block reduction.
    #pragma unroll
    for (int off = 32; off > 0; off >>= 1)
        lsum += __shfl_down(lsum, off, 64);
    if (lane == 0) s_red[wave] = lsum;
    __syncthreads();
    if (t == 0)
        partials[bid] = (s_red[0] + s_red[1]) + (s_red[2] + s_red[3]);
}

// Deterministic final reduction of 2048 block partials -> mean.
__global__ __launch_bounds__(256) void psl_finish(
    const float* __restrict__ partials,
    float*       __restrict__ dout)
{
    __shared__ float s_red[4];
    const int t = threadIdx.x;
    float s = ((partials[t]        + partials[t + 256]) +
               (partials[t + 512]  + partials[t + 768])) +
              ((partials[t + 1024] + partials[t + 1280]) +
               (partials[t + 1536] + partials[t + 1792]));
    #pragma unroll
    for (int off = 32; off > 0; off >>= 1)
        s += __shfl_down(s, off, 64);
    if ((t & 63) == 0) s_red[t >> 6] = s;
    __syncthreads();
    if (t == 0)
        dout[0] = ((s_red[0] + s_red[1]) + (s_red[2] + s_red[3])) *
                  (1.0f / (float)(B * H * W));
}

extern "C" void kernel_launch(void* const* d_in, const int* in_sizes, int n_in,
                              void* d_out, int out_size, void* d_ws, size_t ws_size,
                              hipStream_t stream) {
    const float* out_logits = (const float*)d_in[0];
    const int*   pos        = (const int*)d_in[1];
    const int*   neg        = (const int*)d_in[2];
    float* dout     = (float*)d_out;
    float* partials = (float*)d_ws;   // 2048 floats

    psl_main<<<NBLOCKS, 256, 0, stream>>>(out_logits, pos, neg, dout, partials);
    psl_finish<<<1, 256, 0, stream>>>(partials, dout);
}